// Round 17
// baseline (207.565 us; speedup 1.0000x reference)
//
#include <hip/hip_runtime.h>

#define S_LEN 2048
#define NH 16
#define DIM 128
#define KSZ 32
#define STRD 16
#define SSZ 64
#define NSELB 32
#define NCMP 127
#define TOPN 16
#define WINSZ 512
#define NEGF (-1e30f)
#define NEGTH (-1e29f)
#define SCALE 0.088388347648318447f
#define SCALE2 (0.088388347648318447f * 1.4426950408889634f)   // log2-domain

typedef __attribute__((ext_vector_type(8))) short bf16x8;
typedef __attribute__((ext_vector_type(4))) float f32x4;

__device__ __forceinline__ unsigned short f2bf(float f) {
  unsigned u = __builtin_bit_cast(unsigned, f);
  return (unsigned short)((u + 0x7FFFu + ((u >> 16) & 1u)) >> 16);
}
__device__ __forceinline__ float bf2f(unsigned short b) {
  return __builtin_bit_cast(float, (unsigned)b << 16);
}
__device__ __forceinline__ bf16x8 pack8(const float* f) {
  bf16x8 r;
#pragma unroll
  for (int i = 0; i < 8; ++i) r[i] = (short)f2bf(f[i]);
  return r;
}

// sub-padded score layout: 4 groups of 32 cols at stride 33 (bank-spread)
#define SCIDX(r, c) ((r) * 132 + (((c) >> 5) * 33) + ((c) & 31))

// ---------- kernel 1 (fused prep): blocks 0..2047 build vtg/kb;
//            blocks 2048..3071 compress (2 orig compress-blocks each) ----------
// vtg build maps consecutive tid -> consecutive d: v reads 512B-coalesced.
__global__ __launch_bounds__(256) void nsa_prep(
    const float* __restrict__ v, const float* __restrict__ k,
    unsigned short* __restrict__ vtg, unsigned short* __restrict__ kb,
    unsigned short* __restrict__ cmpkh, unsigned short* __restrict__ cmpkl,
    unsigned short* __restrict__ cmpvt) {
  const int b = blockIdx.x;
  const int tid = threadIdx.x;
  if (b < 2048) {
    const int c = b * 256 + tid;
    {
      const int h = c >> 15, tc = (c >> 7) & 255, d = c & 127;
      float f[8];
#pragma unroll
      for (int i = 0; i < 8; ++i) f[i] = v[((tc * 8 + i) * NH + h) * DIM + d];
      *(bf16x8*)(vtg + ((h * DIM + d) * S_LEN + tc * 8)) = pack8(f);
    }
    {
      const int h = c >> 15, t = (c >> 4) & 2047, dc = c & 15;
      const float* src = k + ((t * NH + h) * DIM + dc * 8);
      float f[8];
#pragma unroll
      for (int i = 0; i < 8; ++i) f[i] = src[i];
      *(bf16x8*)(kb + ((h * S_LEN + t) * DIM + dc * 8)) = pack8(f);
    }
  } else {
    const int origbid = (b - 2048) * 2 + (tid >> 7);
    const int c = origbid & 127;
    const int h = origbid >> 7;
    const int d = tid & 127;
    float sk = 0.f, sv = 0.f;
    if (c < NCMP) {
      const int base = ((c * STRD) * NH + h) * DIM + d;
#pragma unroll
      for (int i = 0; i < KSZ; ++i) {
        sk += k[base + i * NH * DIM];
        sv += v[base + i * NH * DIM];
      }
      sk *= (1.0f / KSZ); sv *= (1.0f / KSZ);
    }
    const unsigned short hi = f2bf(sk);
    const unsigned short lo = f2bf(sk - bf2f(hi));
    cmpkh[(h * 128 + c) * 128 + d] = (c < NCMP) ? hi : 0;
    cmpkl[(h * 128 + c) * 128 + d] = (c < NCMP) ? lo : 0;
    cmpvt[(h * 128 + d) * 128 + c] = (c < NCMP) ? f2bf(sv) : 0;
  }
}

// ---------- kernel 2: main fused NSA (R12/R15/R16 structure, measured best) ----------
// One fully-independent 64-thread wave per (h, 16 queries). NO __syncthreads.
// Union tile loop via ctz over a wave-uniform 64-bit active mask; K AND V frags
// both software-pipelined one tile ahead: K loaded right after QK consumes it,
// V loaded right after PV consumes it (full-iteration latency cover, 0 extra regs).
// NOTE: launch_bounds min-waves MUST stay <=2 — higher forces VGPR spill
// (R5/R8/R13 each lost 100-700 µs to this; kernel needs ~112 VGPRs).
__global__ __launch_bounds__(64, 2) void nsa_main(
    const float* __restrict__ q, const float* __restrict__ wg,
    const float* __restrict__ bg, const unsigned short* __restrict__ kb,
    const unsigned short* __restrict__ vtg,
    const unsigned short* __restrict__ cmpkh, const unsigned short* __restrict__ cmpkl,
    const unsigned short* __restrict__ cmpvt, float* __restrict__ out) {
  __shared__ float scw[16 * 132];                  // cmp scores -> probs -> g0*Ocmp
  __shared__ __align__(16) char pa[2112];          // ssel alias; then 2x P bf16 halves
  __shared__ float gatesLds[48];
  __shared__ unsigned maskLds[16];

  const int b = blockIdx.x;
  const int h = ((b & 7) << 1) | ((b >> 3) & 1);   // XCD-pinned head pairs
  const int tq0 = (127 - (b >> 4)) << 4;           // big-work waves first
  const int lane = threadIdx.x;
  const int l15 = lane & 15;
  const int l4 = lane >> 4;

  const int nvmax = tq0 >> 4;
  const int nct0 = (nvmax + 31) >> 5;
  const int nct = (nct0 < 4) ? nct0 : 4;

  if (lane < 16) maskLds[lane] = 0u;

  const unsigned short* kbh = kb + h * S_LEN * DIM;
  const unsigned short* vth = vtg + h * DIM * S_LEN;

  // ---- Q hi fragments ----
  bf16x8 qfh[4];
  const float* qp = q + ((tq0 + l15) * NH + h) * DIM + l4 * 8;
#pragma unroll
  for (int ks = 0; ks < 4; ++ks) {
    float f[8];
#pragma unroll
    for (int i = 0; i < 8; ++i) f[i] = bf2f(f2bf(qp[ks * 32 + i]));
    qfh[ks] = pack8(f);
  }

  // ---- gates (fp32 exact), lanes 0..47 ----
  if (lane < 48) {
    const int qloc = lane / 3, gi = lane % 3;
    const float* qr_ = q + ((tq0 + qloc) * NH + h) * DIM;
    float acc = bg[gi];
#pragma unroll
    for (int d4 = 0; d4 < DIM; d4 += 4) {
      const float4 qv = *(const float4*)(qr_ + d4);
      acc += qv.x * wg[(d4 + 0) * 3 + gi] + qv.y * wg[(d4 + 1) * 3 + gi] +
             qv.z * wg[(d4 + 2) * 3 + gi] + qv.w * wg[(d4 + 3) * 3 + gi];
    }
    gatesLds[qloc * 3 + gi] = 1.0f / (1.0f + __expf(-acc));
  }

  // ---- cmp QK hi/lo over needed ct tiles (e-domain, exact) ----
  {
    bf16x8 qfl[4];
#pragma unroll
    for (int ks = 0; ks < 4; ++ks) {
      float f[8];
#pragma unroll
      for (int i = 0; i < 8; ++i) {
        const float x = qp[ks * 32 + i];
        f[i] = x - bf2f(f2bf(x));
      }
      qfl[ks] = pack8(f);
    }
    for (int ct = 0; ct < nct; ++ct) {
      const unsigned short* bk = cmpkh + (h * 128 + ct * 32) * 128 + l4 * 8;
      const unsigned short* bkl = cmpkl + (h * 128 + ct * 32) * 128 + l4 * 8;
      f32x4 s0 = {0, 0, 0, 0}, s1 = {0, 0, 0, 0};
#pragma unroll
      for (int ks = 0; ks < 4; ++ks) {
        bf16x8 bh0 = *(const bf16x8*)(bk + l15 * 128 + ks * 32);
        bf16x8 bh1 = *(const bf16x8*)(bk + (16 + l15) * 128 + ks * 32);
        bf16x8 bl0 = *(const bf16x8*)(bkl + l15 * 128 + ks * 32);
        bf16x8 bl1 = *(const bf16x8*)(bkl + (16 + l15) * 128 + ks * 32);
        s0 = __builtin_amdgcn_mfma_f32_16x16x32_bf16(qfh[ks], bh0, s0, 0, 0, 0);
        s0 = __builtin_amdgcn_mfma_f32_16x16x32_bf16(qfl[ks], bh0, s0, 0, 0, 0);
        s0 = __builtin_amdgcn_mfma_f32_16x16x32_bf16(qfh[ks], bl0, s0, 0, 0, 0);
        s1 = __builtin_amdgcn_mfma_f32_16x16x32_bf16(qfh[ks], bh1, s1, 0, 0, 0);
        s1 = __builtin_amdgcn_mfma_f32_16x16x32_bf16(qfl[ks], bh1, s1, 0, 0, 0);
        s1 = __builtin_amdgcn_mfma_f32_16x16x32_bf16(qfh[ks], bl1, s1, 0, 0, 0);
      }
#pragma unroll
      for (int j = 0; j < 4; ++j) {
        const int qr = l4 * 4 + j;
        scw[SCIDX(qr, ct * 32 + l15)] = s0[j] * SCALE;
        scw[SCIDX(qr, ct * 32 + 16 + l15)] = s1[j] * SCALE;
      }
    }
  }

  // ---- softmax over 127 cmp scores (4 lanes per query; same wave) ----
  {
    const int qq = lane >> 2, qg = lane & 3;
    const int tq = tq0 + qq;
    const int nv = (tq >= KSZ - 1) ? ((tq - (KSZ - 1)) / STRD + 1) : 0;
    float x[32];
#pragma unroll
    for (int i = 0; i < 32; ++i) x[i] = scw[SCIDX(qq, qg * 32 + i)];
    float m = NEGF;
#pragma unroll
    for (int i = 0; i < 32; ++i)
      if (qg * 32 + i < nv) m = fmaxf(m, x[i]);
    m = fmaxf(m, __shfl_xor(m, 1));
    m = fmaxf(m, __shfl_xor(m, 2));
    float s = 0.f;
#pragma unroll
    for (int i = 0; i < 32; ++i) {
      x[i] = (qg * 32 + i < nv) ? __expf(x[i] - m) : 0.f;
      s += x[i];
    }
    s += __shfl_xor(s, 1);
    s += __shfl_xor(s, 2);
    const float inv = (nv > 0) ? (1.0f / s) : 0.f;
#pragma unroll
    for (int i = 0; i < 32; ++i) scw[SCIDX(qq, qg * 32 + i)] = x[i] * inv;
  }

  // ---- selection scores + top-16 (exact tie semantics); ssel aliases pa ----
  {
    float* ssel = (float*)pa;
    const int qq = lane >> 2, jg = lane & 3;
    const int tq = tq0 + qq;
    float vj[8];
#pragma unroll
    for (int i = 0; i < 8; ++i) {
      const int j = jg * 8 + i;
      const int lo = (4 * j - 1 > 0) ? 4 * j - 1 : 0;
      const int hi = (4 * j + 3 < NCMP - 1) ? 4 * j + 3 : NCMP - 1;
      float ps = 0.f;
      for (int c = lo; c <= hi; ++c) ps += scw[SCIDX(qq, c)];
      float val = (j * SSZ <= tq) ? ps : -1.0f;
      if (j == (tq >> 6)) val += 1e6f;
      vj[i] = val;
      ssel[qq * 33 + j] = val;
    }
    float sv[32];
#pragma unroll
    for (int jp = 0; jp < 32; ++jp) sv[jp] = ssel[qq * 33 + jp];
#pragma unroll
    for (int i = 0; i < 8; ++i) {
      const int j = jg * 8 + i;
      const float my = vj[i];
      int rank = 0;
#pragma unroll
      for (int jp = 0; jp < 32; ++jp)
        rank += (sv[jp] > my) || (sv[jp] == my && jp < j);
      if (rank < TOPN && (j * SSZ <= tq)) atomicOr(&maskLds[qq], 1u << j);
    }
  }

  unsigned maskq[4];
#pragma unroll
  for (int j = 0; j < 4; ++j) maskq[j] = maskLds[l4 * 4 + j];
  unsigned sel16 = maskq[0] | maskq[1] | maskq[2] | maskq[3];
  sel16 |= __shfl_xor(sel16, 16);
  sel16 |= __shfl_xor(sel16, 32);

  // ---- cmp PV -> fold g0*Ocmp into scw ----
  {
    f32x4 accC[8];
#pragma unroll
    for (int n = 0; n < 8; ++n) accC[n] = (f32x4){0, 0, 0, 0};
    for (int ct = 0; ct < nct; ++ct) {
      float f[8];
#pragma unroll
      for (int i = 0; i < 8; ++i) f[i] = scw[SCIDX(l15, ct * 32 + l4 * 8 + i)];
      bf16x8 ap = pack8(f);
      const unsigned short* cvb = cmpvt + (h * 128) * 128 + ct * 32 + l4 * 8;
#pragma unroll
      for (int n = 0; n < 8; ++n) {
        bf16x8 bvv = *(const bf16x8*)(cvb + (n * 16 + l15) * 128);
        accC[n] = __builtin_amdgcn_mfma_f32_16x16x32_bf16(ap, bvv, accC[n], 0, 0, 0);
      }
    }
#pragma unroll
    for (int j = 0; j < 4; ++j) {
      const int qr = l4 * 4 + j;
      const float g0 = gatesLds[qr * 3 + 0];
#pragma unroll
      for (int n = 0; n < 8; ++n) scw[SCIDX(qr, n * 16 + l15)] = g0 * accC[n][j];
    }
  }

  // ---- active-kt mask (wave-uniform): pairs of sel16 bits | window range ----
  const int ktmax = (tq0 + 15) >> 5;
  const int ktw = (tq0 > WINSZ) ? ((tq0 - WINSZ) >> 5) : 0;
  unsigned long long actmask;
  {
    unsigned long long m = (unsigned long long)sel16;
    m = (m | (m << 16)) & 0x0000FFFF0000FFFFull;
    m = (m | (m << 8))  & 0x00FF00FF00FF00FFull;
    m = (m | (m << 4))  & 0x0F0F0F0F0F0F0F0Full;
    m = (m | (m << 2))  & 0x3333333333333333ull;
    m = (m | (m << 1))  & 0x5555555555555555ull;
    const unsigned long long em = m * 3ull;                   // bit j -> 2j,2j+1
    const unsigned long long winm = ~0ull << ktw;
    const unsigned long long rng =
        (ktmax >= 63) ? ~0ull : ((1ull << (ktmax + 1)) - 1ull);
    actmask = (em | winm) & rng;
  }

  // ---- merged union tile loop; K and V both pipelined one tile ahead ----
  f32x4 accS[8], accW[8];
#pragma unroll
  for (int n = 0; n < 8; ++n) { accS[n] = (f32x4){0, 0, 0, 0}; accW[n] = (f32x4){0, 0, 0, 0}; }
  float mS[4], lS[4], mW[4], lW[4];
#pragma unroll
  for (int j = 0; j < 4; ++j) { mS[j] = NEGF; lS[j] = 0.f; mW[j] = NEGF; lW[j] = 0.f; }

  char* paS = pa;
  char* paW = pa + 1024;

  unsigned long long rem = actmask;
  int kt = rem ? __builtin_ctzll(rem) : 0;
  bf16x8 kf[8], bvc[8];
  if (rem) {
    const unsigned short* kbase = kbh + (kt << 5) * DIM + l4 * 8;
#pragma unroll
    for (int ks = 0; ks < 4; ++ks) {
      kf[ks] = *(const bf16x8*)(kbase + l15 * DIM + ks * 32);
      kf[4 + ks] = *(const bf16x8*)(kbase + (16 + l15) * DIM + ks * 32);
    }
    const unsigned short* vbase = vth + (kt << 5) + l4 * 8;
#pragma unroll
    for (int n = 0; n < 8; ++n)
      bvc[n] = *(const bf16x8*)(vbase + (n * 16 + l15) * S_LEN);
  }

  while (rem) {
    rem &= rem - 1ull;
    const int kt0 = kt << 5;
    const int jb = kt >> 1;
    const bool selAct = (sel16 >> jb) & 1u;
    const bool winAct = kt >= ktw;
    const int ktn = rem ? __builtin_ctzll(rem) : -1;

    // QK (K prefetched last iteration)
    __builtin_amdgcn_s_setprio(1);
    f32x4 s0 = {0, 0, 0, 0}, s1 = {0, 0, 0, 0};
#pragma unroll
    for (int ks = 0; ks < 4; ++ks) {
      s0 = __builtin_amdgcn_mfma_f32_16x16x32_bf16(qfh[ks], kf[ks], s0, 0, 0, 0);
      s1 = __builtin_amdgcn_mfma_f32_16x16x32_bf16(qfh[ks], kf[4 + ks], s1, 0, 0, 0);
    }
    __builtin_amdgcn_s_setprio(0);

    // prefetch next active tile's K (kf dead after QK; covered to next QK)
    if (ktn >= 0) {
      const unsigned short* kbase = kbh + (ktn << 5) * DIM + l4 * 8;
#pragma unroll
      for (int ks = 0; ks < 4; ++ks) {
        kf[ks] = *(const bf16x8*)(kbase + l15 * DIM + ks * 32);
        kf[4 + ks] = *(const bf16x8*)(kbase + (16 + l15) * DIM + ks * 32);
      }
    }

    const int c0 = kt0 + l15, c1 = kt0 + 16 + l15;
#pragma unroll
    for (int j = 0; j < 4; ++j) {
      const int qr = l4 * 4 + j;
      const int tq = tq0 + qr;
      const float sv0 = s0[j] * SCALE2, sv1 = s1[j] * SCALE2;   // log2 domain
      if (selAct) {
        const bool mb = (maskq[j] >> jb) & 1u;
        const float v0 = (mb && c0 <= tq) ? sv0 : NEGF;
        const float v1 = (mb && c1 <= tq) ? sv1 : NEGF;
        const float rml = fmaxf(v0, v1);
        if (__any(rml > mS[j] + 11.5416541f)) {
          float rm = rml;
          rm = fmaxf(rm, __shfl_xor(rm, 1));
          rm = fmaxf(rm, __shfl_xor(rm, 2));
          rm = fmaxf(rm, __shfl_xor(rm, 4));
          rm = fmaxf(rm, __shfl_xor(rm, 8));
          if (rm > mS[j]) {
            const float sf = exp2f(mS[j] - rm);
            lS[j] *= sf;
#pragma unroll
            for (int n = 0; n < 8; ++n) accS[n][j] *= sf;
            mS[j] = rm;
          }
        }
        const float p0 = (v0 > NEGTH) ? exp2f(v0 - mS[j]) : 0.f;
        const float p1 = (v1 > NEGTH) ? exp2f(v1 - mS[j]) : 0.f;
        lS[j] += p0 + p1;
        *(unsigned short*)(paS + qr * 64 + ((l15 * 2) ^ (j << 4))) = f2bf(p0);
        *(unsigned short*)(paS + qr * 64 + (((16 + l15) * 2) ^ (j << 4))) = f2bf(p1);
      }
      if (winAct) {
        const float v0 = (c0 <= tq && c0 >= tq - WINSZ) ? sv0 : NEGF;
        const float v1 = (c1 <= tq && c1 >= tq - WINSZ) ? sv1 : NEGF;
        const float rml = fmaxf(v0, v1);
        if (__any(rml > mW[j] + 11.5416541f)) {
          float rm = rml;
          rm = fmaxf(rm, __shfl_xor(rm, 1));
          rm = fmaxf(rm, __shfl_xor(rm, 2));
          rm = fmaxf(rm, __shfl_xor(rm, 4));
          rm = fmaxf(rm, __shfl_xor(rm, 8));
          if (rm > mW[j]) {
            const float sf = exp2f(mW[j] - rm);
            lW[j] *= sf;
#pragma unroll
            for (int n = 0; n < 8; ++n) accW[n][j] *= sf;
            mW[j] = rm;
          }
        }
        const float p0 = (v0 > NEGTH) ? exp2f(v0 - mW[j]) : 0.f;
        const float p1 = (v1 > NEGTH) ? exp2f(v1 - mW[j]) : 0.f;
        lW[j] += p0 + p1;
        *(unsigned short*)(paW + qr * 64 + ((l15 * 2) ^ (j << 4))) = f2bf(p0);
        *(unsigned short*)(paW + qr * 64 + (((16 + l15) * 2) ^ (j << 4))) = f2bf(p1);
      }
    }
    // PV uses V prefetched at the END of the previous iteration (full-iter cover)
    __builtin_amdgcn_s_setprio(1);
    if (selAct) {
      bf16x8 ap = *(const bf16x8*)(paS + l15 * 64 + ((l4 * 16) ^ ((l15 & 3) << 4)));
#pragma unroll
      for (int n = 0; n < 8; ++n)
        accS[n] = __builtin_amdgcn_mfma_f32_16x16x32_bf16(ap, bvc[n], accS[n], 0, 0, 0);
    }
    if (winAct) {
      bf16x8 ap = *(const bf16x8*)(paW + l15 * 64 + ((l4 * 16) ^ ((l15 & 3) << 4)));
#pragma unroll
      for (int n = 0; n < 8; ++n)
        accW[n] = __builtin_amdgcn_mfma_f32_16x16x32_bf16(ap, bvc[n], accW[n], 0, 0, 0);
    }
    __builtin_amdgcn_s_setprio(0);

    // prefetch next active tile's V (bvc dead after PV; covered to next PV)
    if (ktn >= 0) {
      const unsigned short* vbase = vth + (ktn << 5) + l4 * 8;
#pragma unroll
      for (int n = 0; n < 8; ++n)
        bvc[n] = *(const bf16x8*)(vbase + (n * 16 + l15) * S_LEN);
    }
    kt = ktn;
  }

  // ---- epilogue: out = g0*Ocmp + g1*Osel + g2*Owin ----
#pragma unroll
  for (int j = 0; j < 4; ++j) {
    float ls = lS[j], lw = lW[j];
    ls += __shfl_xor(ls, 1); lw += __shfl_xor(lw, 1);
    ls += __shfl_xor(ls, 2); lw += __shfl_xor(lw, 2);
    ls += __shfl_xor(ls, 4); lw += __shfl_xor(lw, 4);
    ls += __shfl_xor(ls, 8); lw += __shfl_xor(lw, 8);
    const int qr = l4 * 4 + j;
    const int tq = tq0 + qr;
    const float rlS = gatesLds[qr * 3 + 1] / ls;
    const float rlW = gatesLds[qr * 3 + 2] / lw;
#pragma unroll
    for (int n = 0; n < 8; ++n)
      out[(tq * NH + h) * DIM + n * 16 + l15] =
          scw[SCIDX(qr, n * 16 + l15)] + accS[n][j] * rlS + accW[n][j] * rlW;
  }
}

extern "C" void kernel_launch(void* const* d_in, const int* in_sizes, int n_in,
                              void* d_out, int out_size, void* d_ws, size_t ws_size,
                              hipStream_t stream) {
  const float* q  = (const float*)d_in[0];
  const float* k  = (const float*)d_in[1];
  const float* v  = (const float*)d_in[2];
  const float* wg = (const float*)d_in[3];
  const float* bg = (const float*)d_in[4];
  float* out = (float*)d_out;

  unsigned short* vtg   = (unsigned short*)d_ws;            // 8 MB
  unsigned short* kb    = vtg + NH * DIM * S_LEN;           // 8 MB
  unsigned short* cmpkh = kb + NH * S_LEN * DIM;            // 512 KB
  unsigned short* cmpkl = cmpkh + NH * 128 * 128;           // 512 KB
  unsigned short* cmpvt = cmpkl + NH * 128 * 128;           // 512 KB

  nsa_prep<<<3072, 256, 0, stream>>>(v, k, vtg, kb, cmpkh, cmpkl, cmpvt);
  nsa_main<<<2048, 64, 0, stream>>>(q, wg, bg, kb, vtg, cmpkh, cmpkl, cmpvt, out);
}

// Round 18
// 201.366 us; speedup vs baseline: 1.0308x; 1.0308x over previous
//
#include <hip/hip_runtime.h>

#define S_LEN 2048
#define NH 16
#define DIM 128
#define KSZ 32
#define STRD 16
#define SSZ 64
#define NSELB 32
#define NCMP 127
#define TOPN 16
#define WINSZ 512
#define NEGF (-1e30f)
#define NEGTH (-1e29f)
#define SCALE 0.088388347648318447f
#define SCALE2 (0.088388347648318447f * 1.4426950408889634f)   // log2-domain

typedef __attribute__((ext_vector_type(8))) short bf16x8;
typedef __attribute__((ext_vector_type(4))) float f32x4;

__device__ __forceinline__ unsigned short f2bf(float f) {
  unsigned u = __builtin_bit_cast(unsigned, f);
  return (unsigned short)((u + 0x7FFFu + ((u >> 16) & 1u)) >> 16);
}
__device__ __forceinline__ float bf2f(unsigned short b) {
  return __builtin_bit_cast(float, (unsigned)b << 16);
}
__device__ __forceinline__ bf16x8 pack8(const float* f) {
  bf16x8 r;
#pragma unroll
  for (int i = 0; i < 8; ++i) r[i] = (short)f2bf(f[i]);
  return r;
}

// sub-padded score layout: 4 groups of 32 cols at stride 33 (bank-spread)
#define SCIDX(r, c) ((r) * 132 + (((c) >> 5) * 33) + ((c) & 31))

// ---------- kernel 1 (fused prep): blocks 0..2047 build vtg/kb;
//            blocks 2048..3071 compress (2 orig compress-blocks each) ----------
// vtg build remapped so consecutive tid -> consecutive d: v reads are
// 512B-coalesced per wave (was 4B-scattered at 8KB stride = 16x read
// amplification); the 16B writes at 4KB stride cost far less (8 MB volume).
__global__ __launch_bounds__(256) void nsa_prep(
    const float* __restrict__ v, const float* __restrict__ k,
    unsigned short* __restrict__ vtg, unsigned short* __restrict__ kb,
    unsigned short* __restrict__ cmpkh, unsigned short* __restrict__ cmpkl,
    unsigned short* __restrict__ cmpvt) {
  const int b = blockIdx.x;
  const int tid = threadIdx.x;
  if (b < 2048) {
    const int c = b * 256 + tid;
    {
      const int h = c >> 15, tc = (c >> 7) & 255, d = c & 127;
      float f[8];
#pragma unroll
      for (int i = 0; i < 8; ++i) f[i] = v[((tc * 8 + i) * NH + h) * DIM + d];
      *(bf16x8*)(vtg + ((h * DIM + d) * S_LEN + tc * 8)) = pack8(f);
    }
    {
      const int h = c >> 15, t = (c >> 4) & 2047, dc = c & 15;
      const float* src = k + ((t * NH + h) * DIM + dc * 8);
      float f[8];
#pragma unroll
      for (int i = 0; i < 8; ++i) f[i] = src[i];
      *(bf16x8*)(kb + ((h * S_LEN + t) * DIM + dc * 8)) = pack8(f);
    }
  } else {
    const int origbid = (b - 2048) * 2 + (tid >> 7);
    const int c = origbid & 127;
    const int h = origbid >> 7;
    const int d = tid & 127;
    float sk = 0.f, sv = 0.f;
    if (c < NCMP) {
      const int base = ((c * STRD) * NH + h) * DIM + d;
#pragma unroll
      for (int i = 0; i < KSZ; ++i) {
        sk += k[base + i * NH * DIM];
        sv += v[base + i * NH * DIM];
      }
      sk *= (1.0f / KSZ); sv *= (1.0f / KSZ);
    }
    const unsigned short hi = f2bf(sk);
    const unsigned short lo = f2bf(sk - bf2f(hi));
    cmpkh[(h * 128 + c) * 128 + d] = (c < NCMP) ? hi : 0;
    cmpkl[(h * 128 + c) * 128 + d] = (c < NCMP) ? lo : 0;
    cmpvt[(h * 128 + d) * 128 + c] = (c < NCMP) ? f2bf(sv) : 0;
  }
}

// ---------- kernel 2: main fused NSA (R12/R15/R16 structure, measured best) ----------
// One fully-independent 64-thread wave per (h, 16 queries). NO __syncthreads.
// Union tile loop via ctz over a wave-uniform 64-bit active mask; K frags
// software-pipelined one tile ahead (L2 latency hides under softmax+PV);
// V loads issued after QK, consumed after softmax (R17's V-pipeline variant
// measured -4.5 µs: longer bvc live range cost more than the cover gained).
// NOTE: launch_bounds min-waves MUST stay <=2 — higher forces VGPR spill
// (R5/R8/R13 each lost 100-700 µs to this; kernel needs ~112 VGPRs).
__global__ __launch_bounds__(64, 2) void nsa_main(
    const float* __restrict__ q, const float* __restrict__ wg,
    const float* __restrict__ bg, const unsigned short* __restrict__ kb,
    const unsigned short* __restrict__ vtg,
    const unsigned short* __restrict__ cmpkh, const unsigned short* __restrict__ cmpkl,
    const unsigned short* __restrict__ cmpvt, float* __restrict__ out) {
  __shared__ float scw[16 * 132];                  // cmp scores -> probs -> g0*Ocmp
  __shared__ __align__(16) char pa[2112];          // ssel alias; then 2x P bf16 halves
  __shared__ float gatesLds[48];
  __shared__ unsigned maskLds[16];

  const int b = blockIdx.x;
  const int h = ((b & 7) << 1) | ((b >> 3) & 1);   // XCD-pinned head pairs
  const int tq0 = (127 - (b >> 4)) << 4;           // big-work waves first
  const int lane = threadIdx.x;
  const int l15 = lane & 15;
  const int l4 = lane >> 4;

  const int nvmax = tq0 >> 4;
  const int nct0 = (nvmax + 31) >> 5;
  const int nct = (nct0 < 4) ? nct0 : 4;

  if (lane < 16) maskLds[lane] = 0u;

  const unsigned short* kbh = kb + h * S_LEN * DIM;
  const unsigned short* vth = vtg + h * DIM * S_LEN;

  // ---- Q hi fragments ----
  bf16x8 qfh[4];
  const float* qp = q + ((tq0 + l15) * NH + h) * DIM + l4 * 8;
#pragma unroll
  for (int ks = 0; ks < 4; ++ks) {
    float f[8];
#pragma unroll
    for (int i = 0; i < 8; ++i) f[i] = bf2f(f2bf(qp[ks * 32 + i]));
    qfh[ks] = pack8(f);
  }

  // ---- gates (fp32 exact), lanes 0..47 ----
  if (lane < 48) {
    const int qloc = lane / 3, gi = lane % 3;
    const float* qr_ = q + ((tq0 + qloc) * NH + h) * DIM;
    float acc = bg[gi];
#pragma unroll
    for (int d4 = 0; d4 < DIM; d4 += 4) {
      const float4 qv = *(const float4*)(qr_ + d4);
      acc += qv.x * wg[(d4 + 0) * 3 + gi] + qv.y * wg[(d4 + 1) * 3 + gi] +
             qv.z * wg[(d4 + 2) * 3 + gi] + qv.w * wg[(d4 + 3) * 3 + gi];
    }
    gatesLds[qloc * 3 + gi] = 1.0f / (1.0f + __expf(-acc));
  }

  // ---- cmp QK hi/lo over needed ct tiles (e-domain, exact) ----
  {
    bf16x8 qfl[4];
#pragma unroll
    for (int ks = 0; ks < 4; ++ks) {
      float f[8];
#pragma unroll
      for (int i = 0; i < 8; ++i) {
        const float x = qp[ks * 32 + i];
        f[i] = x - bf2f(f2bf(x));
      }
      qfl[ks] = pack8(f);
    }
    for (int ct = 0; ct < nct; ++ct) {
      const unsigned short* bk = cmpkh + (h * 128 + ct * 32) * 128 + l4 * 8;
      const unsigned short* bkl = cmpkl + (h * 128 + ct * 32) * 128 + l4 * 8;
      f32x4 s0 = {0, 0, 0, 0}, s1 = {0, 0, 0, 0};
#pragma unroll
      for (int ks = 0; ks < 4; ++ks) {
        bf16x8 bh0 = *(const bf16x8*)(bk + l15 * 128 + ks * 32);
        bf16x8 bh1 = *(const bf16x8*)(bk + (16 + l15) * 128 + ks * 32);
        bf16x8 bl0 = *(const bf16x8*)(bkl + l15 * 128 + ks * 32);
        bf16x8 bl1 = *(const bf16x8*)(bkl + (16 + l15) * 128 + ks * 32);
        s0 = __builtin_amdgcn_mfma_f32_16x16x32_bf16(qfh[ks], bh0, s0, 0, 0, 0);
        s0 = __builtin_amdgcn_mfma_f32_16x16x32_bf16(qfl[ks], bh0, s0, 0, 0, 0);
        s0 = __builtin_amdgcn_mfma_f32_16x16x32_bf16(qfh[ks], bl0, s0, 0, 0, 0);
        s1 = __builtin_amdgcn_mfma_f32_16x16x32_bf16(qfh[ks], bh1, s1, 0, 0, 0);
        s1 = __builtin_amdgcn_mfma_f32_16x16x32_bf16(qfl[ks], bh1, s1, 0, 0, 0);
        s1 = __builtin_amdgcn_mfma_f32_16x16x32_bf16(qfh[ks], bl1, s1, 0, 0, 0);
      }
#pragma unroll
      for (int j = 0; j < 4; ++j) {
        const int qr = l4 * 4 + j;
        scw[SCIDX(qr, ct * 32 + l15)] = s0[j] * SCALE;
        scw[SCIDX(qr, ct * 32 + 16 + l15)] = s1[j] * SCALE;
      }
    }
  }

  // ---- softmax over 127 cmp scores (4 lanes per query; same wave) ----
  {
    const int qq = lane >> 2, qg = lane & 3;
    const int tq = tq0 + qq;
    const int nv = (tq >= KSZ - 1) ? ((tq - (KSZ - 1)) / STRD + 1) : 0;
    float x[32];
#pragma unroll
    for (int i = 0; i < 32; ++i) x[i] = scw[SCIDX(qq, qg * 32 + i)];
    float m = NEGF;
#pragma unroll
    for (int i = 0; i < 32; ++i)
      if (qg * 32 + i < nv) m = fmaxf(m, x[i]);
    m = fmaxf(m, __shfl_xor(m, 1));
    m = fmaxf(m, __shfl_xor(m, 2));
    float s = 0.f;
#pragma unroll
    for (int i = 0; i < 32; ++i) {
      x[i] = (qg * 32 + i < nv) ? __expf(x[i] - m) : 0.f;
      s += x[i];
    }
    s += __shfl_xor(s, 1);
    s += __shfl_xor(s, 2);
    const float inv = (nv > 0) ? (1.0f / s) : 0.f;
#pragma unroll
    for (int i = 0; i < 32; ++i) scw[SCIDX(qq, qg * 32 + i)] = x[i] * inv;
  }

  // ---- selection scores + top-16 (exact tie semantics); ssel aliases pa ----
  {
    float* ssel = (float*)pa;
    const int qq = lane >> 2, jg = lane & 3;
    const int tq = tq0 + qq;
    float vj[8];
#pragma unroll
    for (int i = 0; i < 8; ++i) {
      const int j = jg * 8 + i;
      const int lo = (4 * j - 1 > 0) ? 4 * j - 1 : 0;
      const int hi = (4 * j + 3 < NCMP - 1) ? 4 * j + 3 : NCMP - 1;
      float ps = 0.f;
      for (int c = lo; c <= hi; ++c) ps += scw[SCIDX(qq, c)];
      float val = (j * SSZ <= tq) ? ps : -1.0f;
      if (j == (tq >> 6)) val += 1e6f;
      vj[i] = val;
      ssel[qq * 33 + j] = val;
    }
    float sv[32];
#pragma unroll
    for (int jp = 0; jp < 32; ++jp) sv[jp] = ssel[qq * 33 + jp];
#pragma unroll
    for (int i = 0; i < 8; ++i) {
      const int j = jg * 8 + i;
      const float my = vj[i];
      int rank = 0;
#pragma unroll
      for (int jp = 0; jp < 32; ++jp)
        rank += (sv[jp] > my) || (sv[jp] == my && jp < j);
      if (rank < TOPN && (j * SSZ <= tq)) atomicOr(&maskLds[qq], 1u << j);
    }
  }

  unsigned maskq[4];
#pragma unroll
  for (int j = 0; j < 4; ++j) maskq[j] = maskLds[l4 * 4 + j];
  unsigned sel16 = maskq[0] | maskq[1] | maskq[2] | maskq[3];
  sel16 |= __shfl_xor(sel16, 16);
  sel16 |= __shfl_xor(sel16, 32);

  // ---- cmp PV -> fold g0*Ocmp into scw ----
  {
    f32x4 accC[8];
#pragma unroll
    for (int n = 0; n < 8; ++n) accC[n] = (f32x4){0, 0, 0, 0};
    for (int ct = 0; ct < nct; ++ct) {
      float f[8];
#pragma unroll
      for (int i = 0; i < 8; ++i) f[i] = scw[SCIDX(l15, ct * 32 + l4 * 8 + i)];
      bf16x8 ap = pack8(f);
      const unsigned short* cvb = cmpvt + (h * 128) * 128 + ct * 32 + l4 * 8;
#pragma unroll
      for (int n = 0; n < 8; ++n) {
        bf16x8 bvv = *(const bf16x8*)(cvb + (n * 16 + l15) * 128);
        accC[n] = __builtin_amdgcn_mfma_f32_16x16x32_bf16(ap, bvv, accC[n], 0, 0, 0);
      }
    }
#pragma unroll
    for (int j = 0; j < 4; ++j) {
      const int qr = l4 * 4 + j;
      const float g0 = gatesLds[qr * 3 + 0];
#pragma unroll
      for (int n = 0; n < 8; ++n) scw[SCIDX(qr, n * 16 + l15)] = g0 * accC[n][j];
    }
  }

  // ---- active-kt mask (wave-uniform): pairs of sel16 bits | window range ----
  const int ktmax = (tq0 + 15) >> 5;
  const int ktw = (tq0 > WINSZ) ? ((tq0 - WINSZ) >> 5) : 0;
  unsigned long long actmask;
  {
    unsigned long long m = (unsigned long long)sel16;
    m = (m | (m << 16)) & 0x0000FFFF0000FFFFull;
    m = (m | (m << 8))  & 0x00FF00FF00FF00FFull;
    m = (m | (m << 4))  & 0x0F0F0F0F0F0F0F0Full;
    m = (m | (m << 2))  & 0x3333333333333333ull;
    m = (m | (m << 1))  & 0x5555555555555555ull;
    const unsigned long long em = m * 3ull;                   // bit j -> 2j,2j+1
    const unsigned long long winm = ~0ull << ktw;
    const unsigned long long rng =
        (ktmax >= 63) ? ~0ull : ((1ull << (ktmax + 1)) - 1ull);
    actmask = (em | winm) & rng;
  }

  // ---- merged union tile loop, K software-pipelined one tile ahead ----
  f32x4 accS[8], accW[8];
#pragma unroll
  for (int n = 0; n < 8; ++n) { accS[n] = (f32x4){0, 0, 0, 0}; accW[n] = (f32x4){0, 0, 0, 0}; }
  float mS[4], lS[4], mW[4], lW[4];
#pragma unroll
  for (int j = 0; j < 4; ++j) { mS[j] = NEGF; lS[j] = 0.f; mW[j] = NEGF; lW[j] = 0.f; }

  char* paS = pa;
  char* paW = pa + 1024;

  unsigned long long rem = actmask;
  int kt = rem ? __builtin_ctzll(rem) : 0;
  bf16x8 kf[8];
  if (rem) {
    const unsigned short* kbase = kbh + (kt << 5) * DIM + l4 * 8;
#pragma unroll
    for (int ks = 0; ks < 4; ++ks) {
      kf[ks] = *(const bf16x8*)(kbase + l15 * DIM + ks * 32);
      kf[4 + ks] = *(const bf16x8*)(kbase + (16 + l15) * DIM + ks * 32);
    }
  }

  while (rem) {
    rem &= rem - 1ull;
    const int kt0 = kt << 5;
    const int jb = kt >> 1;
    const bool selAct = (sel16 >> jb) & 1u;
    const bool winAct = kt >= ktw;
    const int ktn = rem ? __builtin_ctzll(rem) : -1;

    // QK (prefetched K)
    __builtin_amdgcn_s_setprio(1);
    f32x4 s0 = {0, 0, 0, 0}, s1 = {0, 0, 0, 0};
#pragma unroll
    for (int ks = 0; ks < 4; ++ks) {
      s0 = __builtin_amdgcn_mfma_f32_16x16x32_bf16(qfh[ks], kf[ks], s0, 0, 0, 0);
      s1 = __builtin_amdgcn_mfma_f32_16x16x32_bf16(qfh[ks], kf[4 + ks], s1, 0, 0, 0);
    }
    __builtin_amdgcn_s_setprio(0);

    // V for current tile (in flight during softmax)
    bf16x8 bv[8];
    const unsigned short* vbase = vth + kt0 + l4 * 8;
#pragma unroll
    for (int n = 0; n < 8; ++n)
      bv[n] = *(const bf16x8*)(vbase + (n * 16 + l15) * S_LEN);

    // prefetch next active tile's K (in flight through softmax+PV+loop entry)
    if (ktn >= 0) {
      const unsigned short* kbase = kbh + (ktn << 5) * DIM + l4 * 8;
#pragma unroll
      for (int ks = 0; ks < 4; ++ks) {
        kf[ks] = *(const bf16x8*)(kbase + l15 * DIM + ks * 32);
        kf[4 + ks] = *(const bf16x8*)(kbase + (16 + l15) * DIM + ks * 32);
      }
    }

    const int c0 = kt0 + l15, c1 = kt0 + 16 + l15;
#pragma unroll
    for (int j = 0; j < 4; ++j) {
      const int qr = l4 * 4 + j;
      const int tq = tq0 + qr;
      const float sv0 = s0[j] * SCALE2, sv1 = s1[j] * SCALE2;   // log2 domain
      if (selAct) {
        const bool mb = (maskq[j] >> jb) & 1u;
        const float v0 = (mb && c0 <= tq) ? sv0 : NEGF;
        const float v1 = (mb && c1 <= tq) ? sv1 : NEGF;
        const float rml = fmaxf(v0, v1);
        if (__any(rml > mS[j] + 11.5416541f)) {
          float rm = rml;
          rm = fmaxf(rm, __shfl_xor(rm, 1));
          rm = fmaxf(rm, __shfl_xor(rm, 2));
          rm = fmaxf(rm, __shfl_xor(rm, 4));
          rm = fmaxf(rm, __shfl_xor(rm, 8));
          if (rm > mS[j]) {
            const float sf = exp2f(mS[j] - rm);
            lS[j] *= sf;
#pragma unroll
            for (int n = 0; n < 8; ++n) accS[n][j] *= sf;
            mS[j] = rm;
          }
        }
        const float p0 = (v0 > NEGTH) ? exp2f(v0 - mS[j]) : 0.f;
        const float p1 = (v1 > NEGTH) ? exp2f(v1 - mS[j]) : 0.f;
        lS[j] += p0 + p1;
        *(unsigned short*)(paS + qr * 64 + ((l15 * 2) ^ (j << 4))) = f2bf(p0);
        *(unsigned short*)(paS + qr * 64 + (((16 + l15) * 2) ^ (j << 4))) = f2bf(p1);
      }
      if (winAct) {
        const float v0 = (c0 <= tq && c0 >= tq - WINSZ) ? sv0 : NEGF;
        const float v1 = (c1 <= tq && c1 >= tq - WINSZ) ? sv1 : NEGF;
        const float rml = fmaxf(v0, v1);
        if (__any(rml > mW[j] + 11.5416541f)) {
          float rm = rml;
          rm = fmaxf(rm, __shfl_xor(rm, 1));
          rm = fmaxf(rm, __shfl_xor(rm, 2));
          rm = fmaxf(rm, __shfl_xor(rm, 4));
          rm = fmaxf(rm, __shfl_xor(rm, 8));
          if (rm > mW[j]) {
            const float sf = exp2f(mW[j] - rm);
            lW[j] *= sf;
#pragma unroll
            for (int n = 0; n < 8; ++n) accW[n][j] *= sf;
            mW[j] = rm;
          }
        }
        const float p0 = (v0 > NEGTH) ? exp2f(v0 - mW[j]) : 0.f;
        const float p1 = (v1 > NEGTH) ? exp2f(v1 - mW[j]) : 0.f;
        lW[j] += p0 + p1;
        *(unsigned short*)(paW + qr * 64 + ((l15 * 2) ^ (j << 4))) = f2bf(p0);
        *(unsigned short*)(paW + qr * 64 + (((16 + l15) * 2) ^ (j << 4))) = f2bf(p1);
      }
    }
    __builtin_amdgcn_s_setprio(1);
    if (selAct) {
      bf16x8 ap = *(const bf16x8*)(paS + l15 * 64 + ((l4 * 16) ^ ((l15 & 3) << 4)));
#pragma unroll
      for (int n = 0; n < 8; ++n)
        accS[n] = __builtin_amdgcn_mfma_f32_16x16x32_bf16(ap, bv[n], accS[n], 0, 0, 0);
    }
    if (winAct) {
      bf16x8 ap = *(const bf16x8*)(paW + l15 * 64 + ((l4 * 16) ^ ((l15 & 3) << 4)));
#pragma unroll
      for (int n = 0; n < 8; ++n)
        accW[n] = __builtin_amdgcn_mfma_f32_16x16x32_bf16(ap, bv[n], accW[n], 0, 0, 0);
    }
    __builtin_amdgcn_s_setprio(0);
    kt = ktn;
  }

  // ---- epilogue: out = g0*Ocmp + g1*Osel + g2*Owin ----
#pragma unroll
  for (int j = 0; j < 4; ++j) {
    float ls = lS[j], lw = lW[j];
    ls += __shfl_xor(ls, 1); lw += __shfl_xor(lw, 1);
    ls += __shfl_xor(ls, 2); lw += __shfl_xor(lw, 2);
    ls += __shfl_xor(ls, 4); lw += __shfl_xor(lw, 4);
    ls += __shfl_xor(ls, 8); lw += __shfl_xor(lw, 8);
    const int qr = l4 * 4 + j;
    const int tq = tq0 + qr;
    const float rlS = gatesLds[qr * 3 + 1] / ls;
    const float rlW = gatesLds[qr * 3 + 2] / lw;
#pragma unroll
    for (int n = 0; n < 8; ++n)
      out[(tq * NH + h) * DIM + n * 16 + l15] =
          scw[SCIDX(qr, n * 16 + l15)] + accS[n][j] * rlS + accW[n][j] * rlW;
  }
}

extern "C" void kernel_launch(void* const* d_in, const int* in_sizes, int n_in,
                              void* d_out, int out_size, void* d_ws, size_t ws_size,
                              hipStream_t stream) {
  const float* q  = (const float*)d_in[0];
  const float* k  = (const float*)d_in[1];
  const float* v  = (const float*)d_in[2];
  const float* wg = (const float*)d_in[3];
  const float* bg = (const float*)d_in[4];
  float* out = (float*)d_out;

  unsigned short* vtg   = (unsigned short*)d_ws;            // 8 MB
  unsigned short* kb    = vtg + NH * DIM * S_LEN;           // 8 MB
  unsigned short* cmpkh = kb + NH * S_LEN * DIM;            // 512 KB
  unsigned short* cmpkl = cmpkh + NH * 128 * 128;           // 512 KB
  unsigned short* cmpvt = cmpkl + NH * 128 * 128;           // 512 KB

  nsa_prep<<<3072, 256, 0, stream>>>(v, k, vtg, kb, cmpkh, cmpkl, cmpvt);
  nsa_main<<<2048, 64, 0, stream>>>(q, wg, bg, kb, vtg, cmpkh, cmpkl, cmpvt, out);
}